// Round 11
// baseline (266.305 us; speedup 1.0000x reference)
//
#include <hip/hip_runtime.h>

typedef __attribute__((ext_vector_type(8))) short bfrag;   // 8 bf16 (4 VGPRs) MFMA operand
typedef __attribute__((ext_vector_type(4))) short s4;      // 4 bf16 (2 VGPRs) 16x16x16 operand
typedef __attribute__((ext_vector_type(4))) float f4;      // MFMA accumulator
typedef unsigned short u16;
typedef __attribute__((ext_vector_type(4))) unsigned short u16x4;

#define L2T 0.20762050593046f   // log2(10000)/64

__device__ inline u16 f2bf(float x) {
    unsigned u = __builtin_bit_cast(unsigned, x);
    u += 0x7FFFu + ((u >> 16) & 1u);   // round-to-nearest-even
    return (u16)(u >> 16);
}

__device__ inline void gload16(const u16* g, u16* l) {
    // async global->LDS, 16B/lane; LDS dst = wave-uniform base + lane*16
    __builtin_amdgcn_global_load_lds((const __attribute__((address_space(1))) u16*)g,
                                     (__attribute__((address_space(3))) u16*)l, 16, 0, 0);
}

// ---------------- fused prep: cast X/wq/wk/wv/wo -> bf16, concat biases ----------------
__global__ __launch_bounds__(256) void prep(const float* __restrict__ X,  const float* __restrict__ wq,
                                            const float* __restrict__ wk, const float* __restrict__ wv,
                                            const float* __restrict__ wo, const float* __restrict__ bq,
                                            const float* __restrict__ bk, const float* __restrict__ bv,
                                            u16* __restrict__ Xb, u16* __restrict__ Wqkv,
                                            u16* __restrict__ Wo_, float* __restrict__ biasqkv) {
    const int v = blockIdx.x * 256 + threadIdx.x;
    const float* src; u16* dst; int idx;
    if (v < 1048576)      { src = X;  dst = Xb;              idx = v; }
    else if (v < 2097152) { src = wq; dst = Wqkv;            idx = v - 1048576; }
    else if (v < 2359296) { src = wk; dst = Wqkv + 4194304;  idx = v - 2097152; }
    else if (v < 2621440) { src = wv; dst = Wqkv + 5242880;  idx = v - 2359296; }
    else if (v < 3670016) { src = wo; dst = Wo_;             idx = v - 2621440; }
    else {
        const int b = v - 3670016;   // 768 float4 = 3072 bias floats
        const float* s = (b < 512) ? (bq + b * 4) : (b < 640) ? (bk + (b - 512) * 4) : (bv + (b - 640) * 4);
        *(float4*)(biasqkv + b * 4) = *(const float4*)s;
        return;
    }
    float4 t = *(const float4*)(src + (size_t)idx * 4);
    u16x4 o;
    o.x = f2bf(t.x); o.y = f2bf(t.y); o.z = f2bf(t.z); o.w = f2bf(t.w);
    *(u16x4*)(dst + (size_t)idx * 4) = o;
}

// ---------------- fused QKV GEMM + bias + RoPE + repack ----------------
// C = Xb[2048][2048] * Wqkv[3072][2048]^T. 64x128 tiles -> grid 24x32 = 768 blocks =
// 3 blocks/CU (48KB LDS x3 = 144 <= 160KB; co-residency is the N=2048 lever, round 8).
// 2x2 wave grid -- wave (wm,wn) owns 32 rows x 64 SPLIT cols, acc[2][4]. RoPE in-lane
// pairing via SPLIT col set: wave wn owns cols jcol(j) = wn*32 + (j&1)*16 + (j>>1)*64,
// so partners (ip, ip+64) are acc[i][j2] <-> acc[i][j2+2] with ip = wn*32 + j2*16 + l16.
// tn: 0..15 Q head tn, 16..19 K head tn-16, 20..23 V kv-head tn-20 (transposed to Vt).
// Depth-3 counted-vmcnt pipeline: 3 loads/stage -> steady vmcnt(6), tail 3 -> 0.
__global__ __launch_bounds__(256) void gemm_qkv_rope(const u16* __restrict__ A, const u16* __restrict__ B,
                                                     const float* __restrict__ bias,
                                                     u16* __restrict__ Qr, u16* __restrict__ Kr,
                                                     u16* __restrict__ Vt) {
    const int K = 2048;
    const int NT = 64;                 // K/32
    __shared__ u16 As[4][64 * 32];     // 16 KB
    __shared__ u16 Bs[4][128 * 32];    // 32 KB
    const int tm = blockIdx.y, tn = blockIdx.x;
    const int tid = threadIdx.x;
    const int w = tid >> 6, lane = tid & 63, quad = lane >> 4, l16 = lane & 15;
    const int wm = w >> 1, wn = w & 1;

    f4 acc[2][4];
#pragma unroll
    for (int i = 0; i < 2; i++)
#pragma unroll
        for (int j = 0; j < 4; j++) acc[i][j] = f4{0.f, 0.f, 0.f, 0.f};

    // staging: A tile 64x32 (1 gload16/thread), B 128x32 (2/thread)
    const u16* aPtr = A + (size_t)(tm * 64 + w * 16 + (lane >> 2)) * K + (lane & 3) * 8;
    const u16* bPtr = B + (size_t)(tn * 128 + w * 32 + (lane >> 2)) * K + (lane & 3) * 8;
    const size_t rowskip = (size_t)16 * K;

    auto stage = [&](int buf, int kk) {
        gload16(aPtr + kk,           &As[buf][(w * 16) * 32]);
        gload16(bPtr + kk,           &Bs[buf][(w * 32) * 32]);
        gload16(bPtr + kk + rowskip, &Bs[buf][(w * 32 + 16) * 32]);
    };

    stage(0, 0); stage(1, 32); stage(2, 64);
    asm volatile("s_waitcnt vmcnt(6)" ::: "memory");   // tile 0 landed; 1,2 in flight
    __builtin_amdgcn_s_barrier();
    asm volatile("" ::: "memory");

    for (int t = 0; t < NT; t++) {
        const int cur = t & 3;
        if (t + 3 < NT) stage((t + 3) & 3, (t + 3) * 32);

        bfrag af[2], bf[4];
#pragma unroll
        for (int i = 0; i < 2; i++)
            af[i] = *(const bfrag*)(&As[cur][(wm * 32 + i * 16 + l16) * 32 + quad * 8]);
#pragma unroll
        for (int j = 0; j < 4; j++) {
            const int jc = wn * 32 + (j & 1) * 16 + (j >> 1) * 64;   // split col set
            bf[j] = *(const bfrag*)(&Bs[cur][(jc + l16) * 32 + quad * 8]);
        }
#pragma unroll
        for (int i = 0; i < 2; i++)
#pragma unroll
            for (int j = 0; j < 4; j++)
                acc[i][j] = __builtin_amdgcn_mfma_f32_16x16x32_bf16(af[i], bf[j], acc[i][j], 0, 0, 0);

        if (t + 3 < NT)      asm volatile("s_waitcnt vmcnt(6)" ::: "memory");  // t+1 landed
        else if (t + 2 < NT) asm volatile("s_waitcnt vmcnt(3)" ::: "memory");
        else if (t + 1 < NT) asm volatile("s_waitcnt vmcnt(0)" ::: "memory");
        if (t + 1 < NT) {
            __builtin_amdgcn_s_barrier();
            asm volatile("" ::: "memory");
        }
    }

    // ---- epilogue ----
    if (tn < 20) {   // Q or K: bias + RoPE + head-major write
        const int qk = (tn < 16);
        const int hd = qk ? tn : (tn - 16);
        u16* base = qk ? (Qr + (size_t)hd * 2048 * 128) : (Kr + (size_t)hd * 2048 * 128);
        float bia0[2], bia1[2], inv[2];
#pragma unroll
        for (int j2 = 0; j2 < 2; j2++) {
            const int ip = wn * 32 + j2 * 16 + l16;        // in [0,64)
            bia0[j2] = bias[tn * 128 + ip];
            bia1[j2] = bias[tn * 128 + ip + 64];
            inv[j2] = exp2f(-(float)ip * L2T);
        }
#pragma unroll
        for (int i = 0; i < 2; i++) {
            const int s0 = tm * 64 + wm * 32 + i * 16 + quad * 4;
#pragma unroll
            for (int r = 0; r < 4; r++) {
                const int s = s0 + r;
                const float fs = (float)s;
                u16* rowp = base + (size_t)s * 128;
#pragma unroll
                for (int j2 = 0; j2 < 2; j2++) {
                    const int ip = wn * 32 + j2 * 16 + l16;
                    float sn, cs;
                    __sincosf(fs * inv[j2], &sn, &cs);
                    const float a0 = acc[i][j2][r] + bia0[j2];       // col ip
                    const float a1 = acc[i][j2 + 2][r] + bia1[j2];   // col ip+64
                    rowp[ip]      = f2bf(a0 * cs - a1 * sn);
                    rowp[ip + 64] = f2bf(a1 * cs + a0 * sn);
                }
            }
        }
    } else {         // V: bias + transposed write to Vt[4][128][2048]
        const int kvh = tn - 20;
        const int s0 = tm * 64 + wm * 32 + quad * 4;
#pragma unroll
        for (int j = 0; j < 4; j++) {
            const int d = wn * 32 + (j & 1) * 16 + (j >> 1) * 64 + l16;
            const float bv = bias[tn * 128 + d];
            u16* basep = Vt + ((size_t)(kvh * 128 + d)) * 2048;
#pragma unroll
            for (int i = 0; i < 2; i++) {
                u16x4 o;
#pragma unroll
                for (int r = 0; r < 4; r++) o[r] = f2bf(acc[i][j][r] + bv);
                *(u16x4*)(basep + s0 + i * 16) = o;
            }
        }
    }
}

// ---------------- GEMM: C[M][N] = A[M][K](bf16) * B[N][K]^T(bf16), fp32 out ----------------
// 64x128 tile -> grid 16x32 = 512 blocks = 2 blocks/CU. 2x2 wave grid, wave (wm,wn) owns
// 32 rows x 64 contiguous cols, acc[2][4]. Depth-3 counted-vmcnt pipeline, 3 loads/stage.
__global__ __launch_bounds__(256) void gemm_bt(const u16* __restrict__ A, const u16* __restrict__ B,
                                               float* __restrict__ C, int M, int N, int K) {
    __shared__ u16 As[4][64 * 32];     // 16 KB
    __shared__ u16 Bs[4][128 * 32];    // 32 KB
    const int tm = blockIdx.y, tn = blockIdx.x;
    const int tid = threadIdx.x;
    const int w = tid >> 6, lane = tid & 63, quad = lane >> 4, l16 = lane & 15;
    const int wm = w >> 1, wn = w & 1;
    const int NT = K >> 5;

    f4 acc[2][4];
#pragma unroll
    for (int i = 0; i < 2; i++)
#pragma unroll
        for (int j = 0; j < 4; j++) acc[i][j] = f4{0.f, 0.f, 0.f, 0.f};

    const u16* aPtr = A + (size_t)(tm * 64 + w * 16 + (lane >> 2)) * K + (lane & 3) * 8;
    const u16* bPtr = B + (size_t)(tn * 128 + w * 32 + (lane >> 2)) * K + (lane & 3) * 8;
    const size_t rowskip = (size_t)16 * K;

    auto stage = [&](int buf, int kk) {
        gload16(aPtr + kk,           &As[buf][(w * 16) * 32]);
        gload16(bPtr + kk,           &Bs[buf][(w * 32) * 32]);
        gload16(bPtr + kk + rowskip, &Bs[buf][(w * 32 + 16) * 32]);
    };

    stage(0, 0); stage(1, 32); stage(2, 64);
    asm volatile("s_waitcnt vmcnt(6)" ::: "memory");   // tile 0 landed; 1,2 in flight
    __builtin_amdgcn_s_barrier();
    asm volatile("" ::: "memory");

    for (int t = 0; t < NT; t++) {
        const int cur = t & 3;
        if (t + 3 < NT) stage((t + 3) & 3, (t + 3) * 32);

        bfrag af[2], bf[4];
#pragma unroll
        for (int i = 0; i < 2; i++)
            af[i] = *(const bfrag*)(&As[cur][(wm * 32 + i * 16 + l16) * 32 + quad * 8]);
#pragma unroll
        for (int j = 0; j < 4; j++)
            bf[j] = *(const bfrag*)(&Bs[cur][(wn * 64 + j * 16 + l16) * 32 + quad * 8]);
#pragma unroll
        for (int i = 0; i < 2; i++)
#pragma unroll
            for (int j = 0; j < 4; j++)
                acc[i][j] = __builtin_amdgcn_mfma_f32_16x16x32_bf16(af[i], bf[j], acc[i][j], 0, 0, 0);

        if (t + 3 < NT)      asm volatile("s_waitcnt vmcnt(6)" ::: "memory");  // t+1 landed
        else if (t + 2 < NT) asm volatile("s_waitcnt vmcnt(3)" ::: "memory");
        else if (t + 1 < NT) asm volatile("s_waitcnt vmcnt(0)" ::: "memory");
        if (t + 1 < NT) {
            __builtin_amdgcn_s_barrier();
            asm volatile("" ::: "memory");
        }
    }

#pragma unroll
    for (int i = 0; i < 2; i++) {
#pragma unroll
        for (int j = 0; j < 4; j++) {
            const int col = tn * 128 + wn * 64 + j * 16 + l16;
#pragma unroll
            for (int r = 0; r < 4; r++) {
                const int row = tm * 64 + wm * 32 + i * 16 + quad * 4 + r;
                C[(size_t)row * N + col] = acc[i][j][r];
            }
        }
    }
}

// ---------------- flash attention (causal), S^T formulation, 128-key tiles ----------------
// ROUND 11: cap max per-block serial work. Round-10's balance analysis: CU time =
// 4.0*min(t1,t2) + 3.4*|t1-t2| us -- a 16-visit block runs mostly SOLO (54us floor), and
// NO static pairing beats ~55 while one block owns 16 serial visits. Fix: heavy q-groups
// (g>=64, 9..16 visits) are split by key-tile parity into 2 partial-blocks (4..8 visits)
// that write unnormalized f32 O-partials + row-sums (streaming softmax => additive);
// light groups (g<64) keep the round-0 direct path. 768 blocks (512 heavy first,
// heaviest-first; 256 light backfill) at 2 resident/CU: the work queue backfills as
// blocks finish -> both CU slots stay busy at the concurrent rate. combine() merges the
// heavy half (rows 1024..2047). Inner loop/body byte-identical to round-0.
// PV C/D layout: oacc[ct][r] = O[q = g*16+l16][d = ct*16+quad*4+r] (f4 walks d).
// Partial layout (f4 units): [h][jj=g-64][ct][quad][l16] (r3-verified index math).
__global__ __launch_bounds__(256) void flash_attn(const u16* __restrict__ Qr, const u16* __restrict__ Kr,
                                                  const u16* __restrict__ Vt, u16* __restrict__ attnout,
                                                  float* __restrict__ opA, float* __restrict__ opB,
                                                  float* __restrict__ psA, float* __restrict__ psB) {
    const int bid = blockIdx.x;
    const bool heavy = (bid < 512);
    int kv, g, sp;
    if (heavy) {
        kv = bid & 3;
        const int rest = bid >> 2;        // 0..127
        g = 127 - (rest >> 1);            // 127..64, heaviest first
        sp = rest & 1;                    // key-tile parity split
    } else {
        const int lid = bid - 512;        // 0..255
        kv = lid & 3;
        g = 63 - (lid >> 2);              // 63..0, heavier lights first
        sp = 0;
    }
    const int step = heavy ? 2 : 1;
    const int tid = threadIdx.x;
    const int w = tid >> 6, lane = tid & 63, quad = lane >> 4, l16 = lane & 15;
    const int h = kv * 4 + w;         // wave's q-head

    __shared__ u16 ks[128 * 128];     // K tile [128 keys][128 d], swizzled 16B chunks
    __shared__ u16 vt[128 * 128];     // V^T tile [128 d][128 keys], swizzled 16B chunks

    // Q fragments (B-operand layout: rows q=l16, k at quad*8)
    bfrag aq[4];
    const u16* qbase = Qr + ((size_t)(h * 2048 + g * 16 + l16)) * 128 + quad * 8;
#pragma unroll
    for (int kb = 0; kb < 4; kb++) aq[kb] = *(const bfrag*)(qbase + kb * 32);

    f4 oacc[8];
#pragma unroll
    for (int ct = 0; ct < 8; ct++) oacc[ct] = f4{0.f, 0.f, 0.f, 0.f};
    float psum = 0.f;                 // per-lane partial row-sum for q = l16

    const int qg = g * 16 + l16;      // this lane's global q row
    const int ktn = g / 8 + 1;        // 128-key tiles for rows [g*16, g*16+16)
    const float C = 0.08838834764831845f * 1.4426950408889634f;  // (1/sqrt(128))*log2(e)
    const u16* kbase = Kr + (size_t)kv * 2048 * 128;
    const u16* vbase = Vt + (size_t)kv * 128 * 2048;

    for (int kt = sp; kt < ktn; kt += step) {
        __syncthreads();
        // stage K [128][128]: 2048 chunks of 16B, 8 per thread
#pragma unroll
        for (int i = 0; i < 8; i++) {
            const int ci = (w * 8 + i) * 64 + lane;
            const int r = ci >> 4, c = (ci & 15) ^ (r & 15);
            gload16(kbase + (size_t)(kt * 128 + r) * 128 + c * 8, &ks[(w * 8 + i) * 512]);
        }
        // stage V^T [128 d][128 keys]: 2048 chunks
#pragma unroll
        for (int i = 0; i < 8; i++) {
            const int ci = (w * 8 + i) * 64 + lane;
            const int r = ci >> 4, c = (ci & 15) ^ (r & 15);
            gload16(vbase + (size_t)r * 2048 + kt * 128 + c * 8, &vt[(w * 8 + i) * 512]);
        }
        __syncthreads();

        // S^T: D[key][q] over 128 keys; A = K-frag (rows key), B = aq
        f4 sc[8];
#pragma unroll
        for (int nt = 0; nt < 8; nt++) {
            f4 c = f4{0.f, 0.f, 0.f, 0.f};
#pragma unroll
            for (int kb = 0; kb < 4; kb++) {
                bfrag a = *(const bfrag*)(&ks[((nt * 16 + l16) * 16 + ((quad + kb * 4) ^ l16)) * 8]);
                c = __builtin_amdgcn_mfma_f32_16x16x32_bf16(a, aq[kb], c, 0, 0, 0);
            }
            sc[nt] = c;
        }

        if (kt == ktn - 1) {          // only the diagonal tile needs causal masking
#pragma unroll
            for (int nt = 0; nt < 8; nt++) {
                const int key = kt * 128 + nt * 16 + quad * 4;
#pragma unroll
                for (int r = 0; r < 4; r++)
                    if (key + r > qg) sc[nt][r] = -INFINITY;
            }
        }

        // streaming softmax + in-lane P pack (A/B-operand layout for 16x16x16)
        s4 pa[8];
#pragma unroll
        for (int nt = 0; nt < 8; nt++) {
#pragma unroll
            for (int r = 0; r < 4; r++) {
                const float p = exp2f(fminf(sc[nt][r] * C, 40.f));
                psum += p;
                pa[nt][r] = (short)f2bf(p);
            }
        }

        // O[q][d] += P*V via 16x16x16: A = V^T frag (rows d), B = P
#pragma unroll
        for (int nt = 0; nt < 8; nt++) {
#pragma unroll
            for (int ct = 0; ct < 8; ct++) {
                const int d = ct * 16 + l16;
                s4 a = *(const s4*)(&vt[(d * 16 + ((nt * 2 + (quad >> 1)) ^ l16)) * 8 + (quad & 1) * 4]);
                oacc[ct] = __builtin_amdgcn_mfma_f32_16x16x16bf16_1k(a, pa[nt], oacc[ct], 0, 0, 0);
            }
        }
    }

    // epilogue: reduce psum over the 4 quads sharing q=l16
    float s = psum;
    s += __shfl_xor(s, 16, 64);
    s += __shfl_xor(s, 32, 64);

    if (heavy) {
        // write unnormalized f32 partials for split sp (additive; combine() merges)
        float* opp = sp ? opB : opA;
        float* psp = sp ? psB : psA;
        const int jj = g - 64;            // 0..63
        if (quad == 0) psp[h * 1024 + jj * 16 + l16] = s;
#pragma unroll
        for (int ct = 0; ct < 8; ct++) {
            const size_t idx = ((((size_t)h * 64 + jj) * 8 + ct) * 4 + quad) * 16 + l16;
            *(f4*)(opp + idx * 4) = oacc[ct];
        }
    } else {
        // light: normalize + direct bf16 store (round-0 path)
        const float inv_l = 1.0f / s;
        u16* orow = attnout + (size_t)qg * 2048 + h * 128;
#pragma unroll
        for (int ct = 0; ct < 8; ct++) {
            u16x4 o;
#pragma unroll
            for (int r = 0; r < 4; r++) o[r] = f2bf(oacc[ct][r] * inv_l);
            *(u16x4*)(orow + ct * 16 + quad * 4) = o;
        }
    }
}

// ---------------- combine: heavy rows only -- attnout = bf16((opA+opB)/(psA+psB)) ------
// 131072 threads; thread t = (h, jj, ct, l16), q = 1024 + jj*16 + l16. 4 coalesced f4
// loads per partial (consecutive l16 -> consecutive 16B units), one scalar denominator,
// 32B contiguous bf16 store. f4 component r maps to d = ct*16 + quad*4 + r.
__global__ __launch_bounds__(256) void combine(const float* __restrict__ opA, const float* __restrict__ opB,
                                               const float* __restrict__ psA, const float* __restrict__ psB,
                                               u16* __restrict__ attnout) {
    const int t = blockIdx.x * 256 + threadIdx.x;   // 0 .. 131071
    const int l16 = t & 15;
    const int ct = (t >> 4) & 7;
    const int jj = (t >> 7) & 63;
    const int h = t >> 13;
    const int q = 1024 + jj * 16 + l16;
    const size_t base = (((size_t)(h * 64 + jj) * 8 + ct) * 256) + (size_t)l16 * 4;

    const float inv = 1.0f / (psA[h * 1024 + jj * 16 + l16] + psB[h * 1024 + jj * 16 + l16]);

    u16x4 ov[4];
#pragma unroll
    for (int quad = 0; quad < 4; quad++) {
        const f4 oa = *(const f4*)(opA + base + quad * 64);
        const f4 ob = *(const f4*)(opB + base + quad * 64);
#pragma unroll
        for (int r = 0; r < 4; r++) ov[quad][r] = f2bf((oa[r] + ob[r]) * inv);
    }
    u16* dst = attnout + (size_t)q * 2048 + h * 128 + ct * 16;
    *(u16x4*)(dst)      = ov[0];
    *(u16x4*)(dst + 4)  = ov[1];
    *(u16x4*)(dst + 8)  = ov[2];
    *(u16x4*)(dst + 12) = ov[3];
}

// ---------------- launch ----------------
extern "C" void kernel_launch(void* const* d_in, const int* in_sizes, int n_in,
                              void* d_out, int out_size, void* d_ws, size_t ws_size,
                              hipStream_t stream) {
    const float* X  = (const float*)d_in[0];
    const float* wq = (const float*)d_in[3];
    const float* bq = (const float*)d_in[4];
    const float* wk = (const float*)d_in[5];
    const float* bk = (const float*)d_in[6];
    const float* wv = (const float*)d_in[7];
    const float* bv = (const float*)d_in[8];
    const float* wo = (const float*)d_in[9];

    char* ws = (char*)d_ws;
    u16*   Xb      = (u16*)(ws);                         // 8 MB  (dead after gemm_qkv_rope)
    u16*   Wqkv    = (u16*)(ws + 8388608);               // 12 MB (dead after gemm_qkv_rope)
    u16*   Wo      = (u16*)(ws + 20971520);              // 8 MB  (live until gemm_bt)
    float* biasqkv = (float*)(ws + 29360128);            // 12 KB
    u16*   Qr      = (u16*)(ws + 54538240);              // 8 MB   [16][2048][128]
    u16*   Kr      = (u16*)(ws + 62926848);              // 2 MB   [4][2048][128]
    u16*   attnout = (u16*)(ws + 67121152);              // 8 MB   [2048][2048]
    u16*   Vt      = (u16*)(ws + 75509760);              // 2 MB   [4][128][2048]
    // flash heavy-half partials reuse the dead Xb/Wqkv region (no footprint growth):
    float* opA     = (float*)(ws);                       // 8 MB  [16][64][8][4][16] f4
    float* opB     = (float*)(ws + 8388608);             // 8 MB
    float* psA     = (float*)(ws + 16777216);            // 64 KB [16][1024]
    float* psB     = (float*)(ws + 16842752);            // 64 KB (ends 16.9MB < 20.97MB)

    prep<<<14339, 256, 0, stream>>>(X, wq, wk, wv, wo, bq, bk, bv, Xb, Wqkv, Wo, biasqkv);
    gemm_qkv_rope<<<dim3(24, 32), 256, 0, stream>>>(Xb, Wqkv, biasqkv, Qr, Kr, Vt);
    flash_attn<<<768, 256, 0, stream>>>(Qr, Kr, Vt, attnout, opA, opB, psA, psB);
    combine<<<512, 256, 0, stream>>>(opA, opB, psA, psB, attnout);
    gemm_bt<<<dim3(16, 32), 256, 0, stream>>>(attnout, Wo, (float*)d_out, 2048, 2048, 2048);
}

// Round 12
// 261.355 us; speedup vs baseline: 1.0189x; 1.0189x over previous
//
#include <hip/hip_runtime.h>

typedef __attribute__((ext_vector_type(8))) short bfrag;   // 8 bf16 (4 VGPRs) MFMA operand
typedef __attribute__((ext_vector_type(4))) short s4;      // 4 bf16 (2 VGPRs) 16x16x16 operand
typedef __attribute__((ext_vector_type(4))) float f4;      // MFMA accumulator
typedef unsigned short u16;
typedef __attribute__((ext_vector_type(4))) unsigned short u16x4;

#define L2T 0.20762050593046f   // log2(10000)/64

__device__ inline u16 f2bf(float x) {
    unsigned u = __builtin_bit_cast(unsigned, x);
    u += 0x7FFFu + ((u >> 16) & 1u);   // round-to-nearest-even
    return (u16)(u >> 16);
}

__device__ inline void gload16(const u16* g, u16* l) {
    // async global->LDS, 16B/lane; LDS dst = wave-uniform base + lane*16
    __builtin_amdgcn_global_load_lds((const __attribute__((address_space(1))) u16*)g,
                                     (__attribute__((address_space(3))) u16*)l, 16, 0, 0);
}

// ---------------- fused prep: cast X/wq/wk/wv/wo -> bf16, concat biases ----------------
__global__ __launch_bounds__(256) void prep(const float* __restrict__ X,  const float* __restrict__ wq,
                                            const float* __restrict__ wk, const float* __restrict__ wv,
                                            const float* __restrict__ wo, const float* __restrict__ bq,
                                            const float* __restrict__ bk, const float* __restrict__ bv,
                                            u16* __restrict__ Xb, u16* __restrict__ Wqkv,
                                            u16* __restrict__ Wo_, float* __restrict__ biasqkv) {
    const int v = blockIdx.x * 256 + threadIdx.x;
    const float* src; u16* dst; int idx;
    if (v < 1048576)      { src = X;  dst = Xb;              idx = v; }
    else if (v < 2097152) { src = wq; dst = Wqkv;            idx = v - 1048576; }
    else if (v < 2359296) { src = wk; dst = Wqkv + 4194304;  idx = v - 2097152; }
    else if (v < 2621440) { src = wv; dst = Wqkv + 5242880;  idx = v - 2359296; }
    else if (v < 3670016) { src = wo; dst = Wo_;             idx = v - 2621440; }
    else {
        const int b = v - 3670016;   // 768 float4 = 3072 bias floats
        const float* s = (b < 512) ? (bq + b * 4) : (b < 640) ? (bk + (b - 512) * 4) : (bv + (b - 640) * 4);
        *(float4*)(biasqkv + b * 4) = *(const float4*)s;
        return;
    }
    float4 t = *(const float4*)(src + (size_t)idx * 4);
    u16x4 o;
    o.x = f2bf(t.x); o.y = f2bf(t.y); o.z = f2bf(t.z); o.w = f2bf(t.w);
    *(u16x4*)(dst + (size_t)idx * 4) = o;
}

// ---------------- fused QKV GEMM + bias + RoPE + repack ----------------
// C = Xb[2048][2048] * Wqkv[3072][2048]^T. 64x128 tiles -> grid 24x32 = 768 blocks =
// 3 blocks/CU (48KB LDS x3 = 144 <= 160KB; co-residency is the N=2048 lever, round 8).
// 2x2 wave grid -- wave (wm,wn) owns 32 rows x 64 SPLIT cols, acc[2][4]. RoPE in-lane
// pairing via SPLIT col set: wave wn owns cols jcol(j) = wn*32 + (j&1)*16 + (j>>1)*64,
// so partners (ip, ip+64) are acc[i][j2] <-> acc[i][j2+2] with ip = wn*32 + j2*16 + l16.
// tn: 0..15 Q head tn, 16..19 K head tn-16, 20..23 V kv-head tn-20 (transposed to Vt).
// Depth-3 counted-vmcnt pipeline: 3 loads/stage -> steady vmcnt(6), tail 3 -> 0.
__global__ __launch_bounds__(256) void gemm_qkv_rope(const u16* __restrict__ A, const u16* __restrict__ B,
                                                     const float* __restrict__ bias,
                                                     u16* __restrict__ Qr, u16* __restrict__ Kr,
                                                     u16* __restrict__ Vt) {
    const int K = 2048;
    const int NT = 64;                 // K/32
    __shared__ u16 As[4][64 * 32];     // 16 KB
    __shared__ u16 Bs[4][128 * 32];    // 32 KB
    const int tm = blockIdx.y, tn = blockIdx.x;
    const int tid = threadIdx.x;
    const int w = tid >> 6, lane = tid & 63, quad = lane >> 4, l16 = lane & 15;
    const int wm = w >> 1, wn = w & 1;

    f4 acc[2][4];
#pragma unroll
    for (int i = 0; i < 2; i++)
#pragma unroll
        for (int j = 0; j < 4; j++) acc[i][j] = f4{0.f, 0.f, 0.f, 0.f};

    // staging: A tile 64x32 (1 gload16/thread), B 128x32 (2/thread)
    const u16* aPtr = A + (size_t)(tm * 64 + w * 16 + (lane >> 2)) * K + (lane & 3) * 8;
    const u16* bPtr = B + (size_t)(tn * 128 + w * 32 + (lane >> 2)) * K + (lane & 3) * 8;
    const size_t rowskip = (size_t)16 * K;

    auto stage = [&](int buf, int kk) {
        gload16(aPtr + kk,           &As[buf][(w * 16) * 32]);
        gload16(bPtr + kk,           &Bs[buf][(w * 32) * 32]);
        gload16(bPtr + kk + rowskip, &Bs[buf][(w * 32 + 16) * 32]);
    };

    stage(0, 0); stage(1, 32); stage(2, 64);
    asm volatile("s_waitcnt vmcnt(6)" ::: "memory");   // tile 0 landed; 1,2 in flight
    __builtin_amdgcn_s_barrier();
    asm volatile("" ::: "memory");

    for (int t = 0; t < NT; t++) {
        const int cur = t & 3;
        if (t + 3 < NT) stage((t + 3) & 3, (t + 3) * 32);

        bfrag af[2], bf[4];
#pragma unroll
        for (int i = 0; i < 2; i++)
            af[i] = *(const bfrag*)(&As[cur][(wm * 32 + i * 16 + l16) * 32 + quad * 8]);
#pragma unroll
        for (int j = 0; j < 4; j++) {
            const int jc = wn * 32 + (j & 1) * 16 + (j >> 1) * 64;   // split col set
            bf[j] = *(const bfrag*)(&Bs[cur][(jc + l16) * 32 + quad * 8]);
        }
#pragma unroll
        for (int i = 0; i < 2; i++)
#pragma unroll
            for (int j = 0; j < 4; j++)
                acc[i][j] = __builtin_amdgcn_mfma_f32_16x16x32_bf16(af[i], bf[j], acc[i][j], 0, 0, 0);

        if (t + 3 < NT)      asm volatile("s_waitcnt vmcnt(6)" ::: "memory");  // t+1 landed
        else if (t + 2 < NT) asm volatile("s_waitcnt vmcnt(3)" ::: "memory");
        else if (t + 1 < NT) asm volatile("s_waitcnt vmcnt(0)" ::: "memory");
        if (t + 1 < NT) {
            __builtin_amdgcn_s_barrier();
            asm volatile("" ::: "memory");
        }
    }

    // ---- epilogue ----
    if (tn < 20) {   // Q or K: bias + RoPE + head-major write
        const int qk = (tn < 16);
        const int hd = qk ? tn : (tn - 16);
        u16* base = qk ? (Qr + (size_t)hd * 2048 * 128) : (Kr + (size_t)hd * 2048 * 128);
        float bia0[2], bia1[2], inv[2];
#pragma unroll
        for (int j2 = 0; j2 < 2; j2++) {
            const int ip = wn * 32 + j2 * 16 + l16;        // in [0,64)
            bia0[j2] = bias[tn * 128 + ip];
            bia1[j2] = bias[tn * 128 + ip + 64];
            inv[j2] = exp2f(-(float)ip * L2T);
        }
#pragma unroll
        for (int i = 0; i < 2; i++) {
            const int s0 = tm * 64 + wm * 32 + i * 16 + quad * 4;
#pragma unroll
            for (int r = 0; r < 4; r++) {
                const int s = s0 + r;
                const float fs = (float)s;
                u16* rowp = base + (size_t)s * 128;
#pragma unroll
                for (int j2 = 0; j2 < 2; j2++) {
                    const int ip = wn * 32 + j2 * 16 + l16;
                    float sn, cs;
                    __sincosf(fs * inv[j2], &sn, &cs);
                    const float a0 = acc[i][j2][r] + bia0[j2];       // col ip
                    const float a1 = acc[i][j2 + 2][r] + bia1[j2];   // col ip+64
                    rowp[ip]      = f2bf(a0 * cs - a1 * sn);
                    rowp[ip + 64] = f2bf(a1 * cs + a0 * sn);
                }
            }
        }
    } else {         // V: bias + transposed write to Vt[4][128][2048]
        const int kvh = tn - 20;
        const int s0 = tm * 64 + wm * 32 + quad * 4;
#pragma unroll
        for (int j = 0; j < 4; j++) {
            const int d = wn * 32 + (j & 1) * 16 + (j >> 1) * 64 + l16;
            const float bv = bias[tn * 128 + d];
            u16* basep = Vt + ((size_t)(kvh * 128 + d)) * 2048;
#pragma unroll
            for (int i = 0; i < 2; i++) {
                u16x4 o;
#pragma unroll
                for (int r = 0; r < 4; r++) o[r] = f2bf(acc[i][j][r] + bv);
                *(u16x4*)(basep + s0 + i * 16) = o;
            }
        }
    }
}

// ---------------- GEMM: C[M][N] = A[M][K](bf16) * B[N][K]^T(bf16), fp32 out ----------------
// 64x128 tile -> grid 16x32 = 512 blocks = 2 blocks/CU. 2x2 wave grid, wave (wm,wn) owns
// 32 rows x 64 contiguous cols, acc[2][4]. Depth-3 counted-vmcnt pipeline, 3 loads/stage.
__global__ __launch_bounds__(256) void gemm_bt(const u16* __restrict__ A, const u16* __restrict__ B,
                                               float* __restrict__ C, int M, int N, int K) {
    __shared__ u16 As[4][64 * 32];     // 16 KB
    __shared__ u16 Bs[4][128 * 32];    // 32 KB
    const int tm = blockIdx.y, tn = blockIdx.x;
    const int tid = threadIdx.x;
    const int w = tid >> 6, lane = tid & 63, quad = lane >> 4, l16 = lane & 15;
    const int wm = w >> 1, wn = w & 1;
    const int NT = K >> 5;

    f4 acc[2][4];
#pragma unroll
    for (int i = 0; i < 2; i++)
#pragma unroll
        for (int j = 0; j < 4; j++) acc[i][j] = f4{0.f, 0.f, 0.f, 0.f};

    const u16* aPtr = A + (size_t)(tm * 64 + w * 16 + (lane >> 2)) * K + (lane & 3) * 8;
    const u16* bPtr = B + (size_t)(tn * 128 + w * 32 + (lane >> 2)) * K + (lane & 3) * 8;
    const size_t rowskip = (size_t)16 * K;

    auto stage = [&](int buf, int kk) {
        gload16(aPtr + kk,           &As[buf][(w * 16) * 32]);
        gload16(bPtr + kk,           &Bs[buf][(w * 32) * 32]);
        gload16(bPtr + kk + rowskip, &Bs[buf][(w * 32 + 16) * 32]);
    };

    stage(0, 0); stage(1, 32); stage(2, 64);
    asm volatile("s_waitcnt vmcnt(6)" ::: "memory");   // tile 0 landed; 1,2 in flight
    __builtin_amdgcn_s_barrier();
    asm volatile("" ::: "memory");

    for (int t = 0; t < NT; t++) {
        const int cur = t & 3;
        if (t + 3 < NT) stage((t + 3) & 3, (t + 3) * 32);

        bfrag af[2], bf[4];
#pragma unroll
        for (int i = 0; i < 2; i++)
            af[i] = *(const bfrag*)(&As[cur][(wm * 32 + i * 16 + l16) * 32 + quad * 8]);
#pragma unroll
        for (int j = 0; j < 4; j++)
            bf[j] = *(const bfrag*)(&Bs[cur][(wn * 64 + j * 16 + l16) * 32 + quad * 8]);
#pragma unroll
        for (int i = 0; i < 2; i++)
#pragma unroll
            for (int j = 0; j < 4; j++)
                acc[i][j] = __builtin_amdgcn_mfma_f32_16x16x32_bf16(af[i], bf[j], acc[i][j], 0, 0, 0);

        if (t + 3 < NT)      asm volatile("s_waitcnt vmcnt(6)" ::: "memory");  // t+1 landed
        else if (t + 2 < NT) asm volatile("s_waitcnt vmcnt(3)" ::: "memory");
        else if (t + 1 < NT) asm volatile("s_waitcnt vmcnt(0)" ::: "memory");
        if (t + 1 < NT) {
            __builtin_amdgcn_s_barrier();
            asm volatile("" ::: "memory");
        }
    }

#pragma unroll
    for (int i = 0; i < 2; i++) {
#pragma unroll
        for (int j = 0; j < 4; j++) {
            const int col = tn * 128 + wn * 64 + j * 16 + l16;
#pragma unroll
            for (int r = 0; r < 4; r++) {
                const int row = tm * 64 + wm * 32 + i * 16 + quad * 4 + r;
                C[(size_t)row * N + col] = acc[i][j][r];
            }
        }
    }
}

// ---------------- flash attention (causal), S^T formulation, 128-key tiles ----------------
// ROUND 12: strict global LPT dispatch order. Cost model (fits r0=64, r10=55, r11=67):
// concurrent CU rate = 2 visits / 4.0us, solo = 1 visit / 3.4us. Round-11 failed because
// its backfill queue ENDED with 8-visit lights -> ~27us solo tail. Fix: all 192 ranks/kv
// ordered globally DESCENDING by visit count (buckets v=8 at rank [0,32), v=7 [32,72),
// v=6 [72,112), v=5 [112,152), v=4 [152,168), v=3/2/1 last) so the queue ends with
// 1-visit blocks (tail <= ~3.4us). Work items: heavy g>=64 parity-split into ceil/floor
// halves (4..8 visits) writing additive f32 partials (r11-verified path); lights g<64
// direct bf16 (round-0 path). Coverage: each heavy (g,sp) + each light g exactly once/kv.
// PV C/D layout: oacc[ct][r] = O[q = g*16+l16][d = ct*16+quad*4+r] (f4 walks d).
// Partial layout (f4 units): [h][jj=g-64][ct][quad][l16].
__global__ __launch_bounds__(256) void flash_attn(const u16* __restrict__ Qr, const u16* __restrict__ Kr,
                                                  const u16* __restrict__ Vt, u16* __restrict__ attnout,
                                                  float* __restrict__ opA, float* __restrict__ opB,
                                                  float* __restrict__ psA, float* __restrict__ psB) {
    const int bid = blockIdx.x;
    const int kv = bid & 3;
    const int r_ = bid >> 2;          // 0..191, global descending visit rank
    int g, sp, step;
    if (r_ < 32) {                    // v=8
        const int o = r_;
        if (o < 16)      { g = 120 + (o & 7);        sp = o >> 3;        step = 2; }
        else if (o < 24) { g = 112 + (o - 16);       sp = 0;             step = 2; }
        else             { g = 56 + (o - 24);        sp = 0;             step = 1; }
    } else if (r_ < 72) {             // v=7
        const int o = r_ - 32;
        if (o < 8)       { g = 112 + o;              sp = 1;             step = 2; }
        else if (o < 24) { g = 104 + ((o - 8) & 7);  sp = (o - 8) >> 3;  step = 2; }
        else if (o < 32) { g = 96 + (o - 24);        sp = 0;             step = 2; }
        else             { g = 48 + (o - 32);        sp = 0;             step = 1; }
    } else if (r_ < 112) {            // v=6
        const int o = r_ - 72;
        if (o < 8)       { g = 96 + o;               sp = 1;             step = 2; }
        else if (o < 24) { g = 88 + ((o - 8) & 7);   sp = (o - 8) >> 3;  step = 2; }
        else if (o < 32) { g = 80 + (o - 24);        sp = 0;             step = 2; }
        else             { g = 40 + (o - 32);        sp = 0;             step = 1; }
    } else if (r_ < 152) {            // v=5
        const int o = r_ - 112;
        if (o < 8)       { g = 80 + o;               sp = 1;             step = 2; }
        else if (o < 24) { g = 72 + ((o - 8) & 7);   sp = (o - 8) >> 3;  step = 2; }
        else if (o < 32) { g = 64 + (o - 24);        sp = 0;             step = 2; }
        else             { g = 32 + (o - 32);        sp = 0;             step = 1; }
    } else if (r_ < 168) {            // v=4
        const int o = r_ - 152;
        if (o < 8)       { g = 64 + o;               sp = 1;             step = 2; }
        else             { g = 24 + (o - 8);         sp = 0;             step = 1; }
    } else if (r_ < 176) { g = 16 + (r_ - 168);      sp = 0;             step = 1; }
    else if (r_ < 184)   { g = 8 + (r_ - 176);       sp = 0;             step = 1; }
    else                 { g = (r_ - 184);           sp = 0;             step = 1; }
    const bool heavy = (step == 2);

    const int tid = threadIdx.x;
    const int w = tid >> 6, lane = tid & 63, quad = lane >> 4, l16 = lane & 15;
    const int h = kv * 4 + w;         // wave's q-head

    __shared__ u16 ks[128 * 128];     // K tile [128 keys][128 d], swizzled 16B chunks
    __shared__ u16 vt[128 * 128];     // V^T tile [128 d][128 keys], swizzled 16B chunks

    // Q fragments (B-operand layout: rows q=l16, k at quad*8)
    bfrag aq[4];
    const u16* qbase = Qr + ((size_t)(h * 2048 + g * 16 + l16)) * 128 + quad * 8;
#pragma unroll
    for (int kb = 0; kb < 4; kb++) aq[kb] = *(const bfrag*)(qbase + kb * 32);

    f4 oacc[8];
#pragma unroll
    for (int ct = 0; ct < 8; ct++) oacc[ct] = f4{0.f, 0.f, 0.f, 0.f};
    float psum = 0.f;                 // per-lane partial row-sum for q = l16

    const int qg = g * 16 + l16;      // this lane's global q row
    const int ktn = g / 8 + 1;        // 128-key tiles for rows [g*16, g*16+16)
    const float C = 0.08838834764831845f * 1.4426950408889634f;  // (1/sqrt(128))*log2(e)
    const u16* kbase = Kr + (size_t)kv * 2048 * 128;
    const u16* vbase = Vt + (size_t)kv * 128 * 2048;

    for (int kt = sp; kt < ktn; kt += step) {
        __syncthreads();
        // stage K [128][128]: 2048 chunks of 16B, 8 per thread
#pragma unroll
        for (int i = 0; i < 8; i++) {
            const int ci = (w * 8 + i) * 64 + lane;
            const int r = ci >> 4, c = (ci & 15) ^ (r & 15);
            gload16(kbase + (size_t)(kt * 128 + r) * 128 + c * 8, &ks[(w * 8 + i) * 512]);
        }
        // stage V^T [128 d][128 keys]: 2048 chunks
#pragma unroll
        for (int i = 0; i < 8; i++) {
            const int ci = (w * 8 + i) * 64 + lane;
            const int r = ci >> 4, c = (ci & 15) ^ (r & 15);
            gload16(vbase + (size_t)r * 2048 + kt * 128 + c * 8, &vt[(w * 8 + i) * 512]);
        }
        __syncthreads();

        // S^T: D[key][q] over 128 keys; A = K-frag (rows key), B = aq
        f4 sc[8];
#pragma unroll
        for (int nt = 0; nt < 8; nt++) {
            f4 c = f4{0.f, 0.f, 0.f, 0.f};
#pragma unroll
            for (int kb = 0; kb < 4; kb++) {
                bfrag a = *(const bfrag*)(&ks[((nt * 16 + l16) * 16 + ((quad + kb * 4) ^ l16)) * 8]);
                c = __builtin_amdgcn_mfma_f32_16x16x32_bf16(a, aq[kb], c, 0, 0, 0);
            }
            sc[nt] = c;
        }

        if (kt == ktn - 1) {          // only the diagonal tile needs causal masking
#pragma unroll
            for (int nt = 0; nt < 8; nt++) {
                const int key = kt * 128 + nt * 16 + quad * 4;
#pragma unroll
                for (int r = 0; r < 4; r++)
                    if (key + r > qg) sc[nt][r] = -INFINITY;
            }
        }

        // streaming softmax + in-lane P pack (A/B-operand layout for 16x16x16)
        s4 pa[8];
#pragma unroll
        for (int nt = 0; nt < 8; nt++) {
#pragma unroll
            for (int r = 0; r < 4; r++) {
                const float p = exp2f(fminf(sc[nt][r] * C, 40.f));
                psum += p;
                pa[nt][r] = (short)f2bf(p);
            }
        }

        // O[q][d] += P*V via 16x16x16: A = V^T frag (rows d), B = P
#pragma unroll
        for (int nt = 0; nt < 8; nt++) {
#pragma unroll
            for (int ct = 0; ct < 8; ct++) {
                const int d = ct * 16 + l16;
                s4 a = *(const s4*)(&vt[(d * 16 + ((nt * 2 + (quad >> 1)) ^ l16)) * 8 + (quad & 1) * 4]);
                oacc[ct] = __builtin_amdgcn_mfma_f32_16x16x16bf16_1k(a, pa[nt], oacc[ct], 0, 0, 0);
            }
        }
    }

    // epilogue: reduce psum over the 4 quads sharing q=l16
    float s = psum;
    s += __shfl_xor(s, 16, 64);
    s += __shfl_xor(s, 32, 64);

    if (heavy) {
        // write unnormalized f32 partials for split sp (additive; combine() merges)
        float* opp = sp ? opB : opA;
        float* psp = sp ? psB : psA;
        const int jj = g - 64;            // 0..63
        if (quad == 0) psp[h * 1024 + jj * 16 + l16] = s;
#pragma unroll
        for (int ct = 0; ct < 8; ct++) {
            const size_t idx = ((((size_t)h * 64 + jj) * 8 + ct) * 4 + quad) * 16 + l16;
            *(f4*)(opp + idx * 4) = oacc[ct];
        }
    } else {
        // light: normalize + direct bf16 store (round-0 path)
        const float inv_l = 1.0f / s;
        u16* orow = attnout + (size_t)qg * 2048 + h * 128;
#pragma unroll
        for (int ct = 0; ct < 8; ct++) {
            u16x4 o;
#pragma unroll
            for (int r = 0; r < 4; r++) o[r] = f2bf(oacc[ct][r] * inv_l);
            *(u16x4*)(orow + ct * 16 + quad * 4) = o;
        }
    }
}

// ---------------- combine: heavy rows only -- attnout = bf16((opA+opB)/(psA+psB)) ------
// 131072 threads; thread t = (h, jj, ct, l16), q = 1024 + jj*16 + l16. 4 coalesced f4
// loads per partial (consecutive l16 -> consecutive 16B units), one scalar denominator,
// 32B contiguous bf16 store. f4 component r maps to d = ct*16 + quad*4 + r.
__global__ __launch_bounds__(256) void combine(const float* __restrict__ opA, const float* __restrict__ opB,
                                               const float* __restrict__ psA, const float* __restrict__ psB,
                                               u16* __restrict__ attnout) {
    const int t = blockIdx.x * 256 + threadIdx.x;   // 0 .. 131071
    const int l16 = t & 15;
    const int ct = (t >> 4) & 7;
    const int jj = (t >> 7) & 63;
    const int h = t >> 13;
    const int q = 1024 + jj * 16 + l16;
    const size_t base = (((size_t)(h * 64 + jj) * 8 + ct) * 256) + (size_t)l16 * 4;

    const float inv = 1.0f / (psA[h * 1024 + jj * 16 + l16] + psB[h * 1024 + jj * 16 + l16]);

    u16x4 ov[4];
#pragma unroll
    for (int quad = 0; quad < 4; quad++) {
        const f4 oa = *(const f4*)(opA + base + quad * 64);
        const f4 ob = *(const f4*)(opB + base + quad * 64);
#pragma unroll
        for (int r = 0; r < 4; r++) ov[quad][r] = f2bf((oa[r] + ob[r]) * inv);
    }
    u16* dst = attnout + (size_t)q * 2048 + h * 128 + ct * 16;
    *(u16x4*)(dst)      = ov[0];
    *(u16x4*)(dst + 4)  = ov[1];
    *(u16x4*)(dst + 8)  = ov[2];
    *(u16x4*)(dst + 12) = ov[3];
}

// ---------------- launch ----------------
extern "C" void kernel_launch(void* const* d_in, const int* in_sizes, int n_in,
                              void* d_out, int out_size, void* d_ws, size_t ws_size,
                              hipStream_t stream) {
    const float* X  = (const float*)d_in[0];
    const float* wq = (const float*)d_in[3];
    const float* bq = (const float*)d_in[4];
    const float* wk = (const float*)d_in[5];
    const float* bk = (const float*)d_in[6];
    const float* wv = (const float*)d_in[7];
    const float* bv = (const float*)d_in[8];
    const float* wo = (const float*)d_in[9];

    char* ws = (char*)d_ws;
    u16*   Xb      = (u16*)(ws);                         // 8 MB  (dead after gemm_qkv_rope)
    u16*   Wqkv    = (u16*)(ws + 8388608);               // 12 MB (dead after gemm_qkv_rope)
    u16*   Wo      = (u16*)(ws + 20971520);              // 8 MB  (live until gemm_bt)
    float* biasqkv = (float*)(ws + 29360128);            // 12 KB
    u16*   Qr      = (u16*)(ws + 54538240);              // 8 MB   [16][2048][128]
    u16*   Kr      = (u16*)(ws + 62926848);              // 2 MB   [4][2048][128]
    u16*   attnout = (u16*)(ws + 67121152);              // 8 MB   [2048][2048]
    u16*   Vt      = (u16*)(ws + 75509760);              // 2 MB   [4][128][2048]
    // flash heavy-half partials reuse the dead Xb/Wqkv region (no footprint growth):
    float* opA     = (float*)(ws);                       // 8 MB  [16][64][8][4][16] f4
    float* opB     = (float*)(ws + 8388608);             // 8 MB
    float* psA     = (float*)(ws + 16777216);            // 64 KB [16][1024]
    float* psB     = (float*)(ws + 16842752);            // 64 KB (ends 16.9MB < 20.97MB)

    prep<<<14339, 256, 0, stream>>>(X, wq, wk, wv, wo, bq, bk, bv, Xb, Wqkv, Wo, biasqkv);
    gemm_qkv_rope<<<dim3(24, 32), 256, 0, stream>>>(Xb, Wqkv, biasqkv, Qr, Kr, Vt);
    flash_attn<<<768, 256, 0, stream>>>(Qr, Kr, Vt, attnout, opA, opB, psA, psB);
    combine<<<512, 256, 0, stream>>>(opA, opB, psA, psB, attnout);
    gemm_bt<<<dim3(16, 32), 256, 0, stream>>>(attnout, Wo, (float*)d_out, 2048, 2048, 2048);
}

// Round 13
// 247.874 us; speedup vs baseline: 1.0744x; 1.0544x over previous
//
#include <hip/hip_runtime.h>

typedef __attribute__((ext_vector_type(8))) short bfrag;   // 8 bf16 (4 VGPRs) MFMA operand
typedef __attribute__((ext_vector_type(4))) short s4;      // 4 bf16 (2 VGPRs) 16x16x16 operand
typedef __attribute__((ext_vector_type(4))) float f4;      // MFMA accumulator
typedef unsigned short u16;
typedef __attribute__((ext_vector_type(4))) unsigned short u16x4;

#define L2T 0.20762050593046f   // log2(10000)/64

__device__ inline u16 f2bf(float x) {
    unsigned u = __builtin_bit_cast(unsigned, x);
    u += 0x7FFFu + ((u >> 16) & 1u);   // round-to-nearest-even
    return (u16)(u >> 16);
}

__device__ inline void gload16(const u16* g, u16* l) {
    // async global->LDS, 16B/lane; LDS dst = wave-uniform base + lane*16
    __builtin_amdgcn_global_load_lds((const __attribute__((address_space(1))) u16*)g,
                                     (__attribute__((address_space(3))) u16*)l, 16, 0, 0);
}

// ---------------- fused prep: cast X/wq/wk/wv/wo -> bf16, concat biases ----------------
// ROUND 13: grid-stride at 2048 blocks (7 iters/thread) instead of 14339 one-shot blocks
// (56 blocks/CU of tiny work = launch overhead on a ~14us memory-bound kernel; G11).
// v->work mapping identical to previous rounds.
__global__ __launch_bounds__(256) void prep(const float* __restrict__ X,  const float* __restrict__ wq,
                                            const float* __restrict__ wk, const float* __restrict__ wv,
                                            const float* __restrict__ wo, const float* __restrict__ bq,
                                            const float* __restrict__ bk, const float* __restrict__ bv,
                                            u16* __restrict__ Xb, u16* __restrict__ Wqkv,
                                            u16* __restrict__ Wo_, float* __restrict__ biasqkv) {
    for (int v = blockIdx.x * 256 + threadIdx.x; v < 3670784; v += 2048 * 256) {
        const float* src; u16* dst; int idx;
        if (v < 1048576)      { src = X;  dst = Xb;              idx = v; }
        else if (v < 2097152) { src = wq; dst = Wqkv;            idx = v - 1048576; }
        else if (v < 2359296) { src = wk; dst = Wqkv + 4194304;  idx = v - 2097152; }
        else if (v < 2621440) { src = wv; dst = Wqkv + 5242880;  idx = v - 2359296; }
        else if (v < 3670016) { src = wo; dst = Wo_;             idx = v - 2621440; }
        else {
            const int b = v - 3670016;   // 768 float4 = 3072 bias floats
            const float* s = (b < 512) ? (bq + b * 4) : (b < 640) ? (bk + (b - 512) * 4) : (bv + (b - 640) * 4);
            *(float4*)(biasqkv + b * 4) = *(const float4*)s;
            continue;
        }
        float4 t = *(const float4*)(src + (size_t)idx * 4);
        u16x4 o;
        o.x = f2bf(t.x); o.y = f2bf(t.y); o.z = f2bf(t.z); o.w = f2bf(t.w);
        *(u16x4*)(dst + (size_t)idx * 4) = o;
    }
}

// ---------------- fused QKV GEMM + bias + RoPE + repack ----------------
// C = Xb[2048][2048] * Wqkv[3072][2048]^T. 64x128 tiles -> grid 24x32 = 768 blocks =
// 3 blocks/CU (48KB LDS x3 = 144 <= 160KB; co-residency is the N=2048 lever, round 8).
// 2x2 wave grid -- wave (wm,wn) owns 32 rows x 64 SPLIT cols, acc[2][4]. RoPE in-lane
// pairing via SPLIT col set: wave wn owns cols jcol(j) = wn*32 + (j&1)*16 + (j>>1)*64,
// so partners (ip, ip+64) are acc[i][j2] <-> acc[i][j2+2] with ip = wn*32 + j2*16 + l16.
// tn: 0..15 Q head tn, 16..19 K head tn-16, 20..23 V kv-head tn-20 (transposed to Vt).
// Depth-3 counted-vmcnt pipeline: 3 loads/stage -> steady vmcnt(6), tail 3 -> 0.
__global__ __launch_bounds__(256) void gemm_qkv_rope(const u16* __restrict__ A, const u16* __restrict__ B,
                                                     const float* __restrict__ bias,
                                                     u16* __restrict__ Qr, u16* __restrict__ Kr,
                                                     u16* __restrict__ Vt) {
    const int K = 2048;
    const int NT = 64;                 // K/32
    __shared__ u16 As[4][64 * 32];     // 16 KB
    __shared__ u16 Bs[4][128 * 32];    // 32 KB
    const int tm = blockIdx.y, tn = blockIdx.x;
    const int tid = threadIdx.x;
    const int w = tid >> 6, lane = tid & 63, quad = lane >> 4, l16 = lane & 15;
    const int wm = w >> 1, wn = w & 1;

    f4 acc[2][4];
#pragma unroll
    for (int i = 0; i < 2; i++)
#pragma unroll
        for (int j = 0; j < 4; j++) acc[i][j] = f4{0.f, 0.f, 0.f, 0.f};

    // staging: A tile 64x32 (1 gload16/thread), B 128x32 (2/thread)
    const u16* aPtr = A + (size_t)(tm * 64 + w * 16 + (lane >> 2)) * K + (lane & 3) * 8;
    const u16* bPtr = B + (size_t)(tn * 128 + w * 32 + (lane >> 2)) * K + (lane & 3) * 8;
    const size_t rowskip = (size_t)16 * K;

    auto stage = [&](int buf, int kk) {
        gload16(aPtr + kk,           &As[buf][(w * 16) * 32]);
        gload16(bPtr + kk,           &Bs[buf][(w * 32) * 32]);
        gload16(bPtr + kk + rowskip, &Bs[buf][(w * 32 + 16) * 32]);
    };

    stage(0, 0); stage(1, 32); stage(2, 64);
    asm volatile("s_waitcnt vmcnt(6)" ::: "memory");   // tile 0 landed; 1,2 in flight
    __builtin_amdgcn_s_barrier();
    asm volatile("" ::: "memory");

    for (int t = 0; t < NT; t++) {
        const int cur = t & 3;
        if (t + 3 < NT) stage((t + 3) & 3, (t + 3) * 32);

        bfrag af[2], bf[4];
#pragma unroll
        for (int i = 0; i < 2; i++)
            af[i] = *(const bfrag*)(&As[cur][(wm * 32 + i * 16 + l16) * 32 + quad * 8]);
#pragma unroll
        for (int j = 0; j < 4; j++) {
            const int jc = wn * 32 + (j & 1) * 16 + (j >> 1) * 64;   // split col set
            bf[j] = *(const bfrag*)(&Bs[cur][(jc + l16) * 32 + quad * 8]);
        }
#pragma unroll
        for (int i = 0; i < 2; i++)
#pragma unroll
            for (int j = 0; j < 4; j++)
                acc[i][j] = __builtin_amdgcn_mfma_f32_16x16x32_bf16(af[i], bf[j], acc[i][j], 0, 0, 0);

        if (t + 3 < NT)      asm volatile("s_waitcnt vmcnt(6)" ::: "memory");  // t+1 landed
        else if (t + 2 < NT) asm volatile("s_waitcnt vmcnt(3)" ::: "memory");
        else if (t + 1 < NT) asm volatile("s_waitcnt vmcnt(0)" ::: "memory");
        if (t + 1 < NT) {
            __builtin_amdgcn_s_barrier();
            asm volatile("" ::: "memory");
        }
    }

    // ---- epilogue ----
    if (tn < 20) {   // Q or K: bias + RoPE + head-major write
        const int qk = (tn < 16);
        const int hd = qk ? tn : (tn - 16);
        u16* base = qk ? (Qr + (size_t)hd * 2048 * 128) : (Kr + (size_t)hd * 2048 * 128);
        float bia0[2], bia1[2], inv[2];
#pragma unroll
        for (int j2 = 0; j2 < 2; j2++) {
            const int ip = wn * 32 + j2 * 16 + l16;        // in [0,64)
            bia0[j2] = bias[tn * 128 + ip];
            bia1[j2] = bias[tn * 128 + ip + 64];
            inv[j2] = exp2f(-(float)ip * L2T);
        }
#pragma unroll
        for (int i = 0; i < 2; i++) {
            const int s0 = tm * 64 + wm * 32 + i * 16 + quad * 4;
#pragma unroll
            for (int r = 0; r < 4; r++) {
                const int s = s0 + r;
                const float fs = (float)s;
                u16* rowp = base + (size_t)s * 128;
#pragma unroll
                for (int j2 = 0; j2 < 2; j2++) {
                    const int ip = wn * 32 + j2 * 16 + l16;
                    float sn, cs;
                    __sincosf(fs * inv[j2], &sn, &cs);
                    const float a0 = acc[i][j2][r] + bia0[j2];       // col ip
                    const float a1 = acc[i][j2 + 2][r] + bia1[j2];   // col ip+64
                    rowp[ip]      = f2bf(a0 * cs - a1 * sn);
                    rowp[ip + 64] = f2bf(a1 * cs + a0 * sn);
                }
            }
        }
    } else {         // V: bias + transposed write to Vt[4][128][2048]
        const int kvh = tn - 20;
        const int s0 = tm * 64 + wm * 32 + quad * 4;
#pragma unroll
        for (int j = 0; j < 4; j++) {
            const int d = wn * 32 + (j & 1) * 16 + (j >> 1) * 64 + l16;
            const float bv = bias[tn * 128 + d];
            u16* basep = Vt + ((size_t)(kvh * 128 + d)) * 2048;
#pragma unroll
            for (int i = 0; i < 2; i++) {
                u16x4 o;
#pragma unroll
                for (int r = 0; r < 4; r++) o[r] = f2bf(acc[i][j][r] + bv);
                *(u16x4*)(basep + s0 + i * 16) = o;
            }
        }
    }
}

// ---------------- GEMM: C[M][N] = A[M][K](bf16) * B[N][K]^T(bf16), fp32 out ----------------
// 64x128 tile -> grid 16x32 = 512 blocks = 2 blocks/CU. 2x2 wave grid, wave (wm,wn) owns
// 32 rows x 64 contiguous cols, acc[2][4]. Depth-3 counted-vmcnt pipeline, 3 loads/stage.
__global__ __launch_bounds__(256) void gemm_bt(const u16* __restrict__ A, const u16* __restrict__ B,
                                               float* __restrict__ C, int M, int N, int K) {
    __shared__ u16 As[4][64 * 32];     // 16 KB
    __shared__ u16 Bs[4][128 * 32];    // 32 KB
    const int tm = blockIdx.y, tn = blockIdx.x;
    const int tid = threadIdx.x;
    const int w = tid >> 6, lane = tid & 63, quad = lane >> 4, l16 = lane & 15;
    const int wm = w >> 1, wn = w & 1;
    const int NT = K >> 5;

    f4 acc[2][4];
#pragma unroll
    for (int i = 0; i < 2; i++)
#pragma unroll
        for (int j = 0; j < 4; j++) acc[i][j] = f4{0.f, 0.f, 0.f, 0.f};

    const u16* aPtr = A + (size_t)(tm * 64 + w * 16 + (lane >> 2)) * K + (lane & 3) * 8;
    const u16* bPtr = B + (size_t)(tn * 128 + w * 32 + (lane >> 2)) * K + (lane & 3) * 8;
    const size_t rowskip = (size_t)16 * K;

    auto stage = [&](int buf, int kk) {
        gload16(aPtr + kk,           &As[buf][(w * 16) * 32]);
        gload16(bPtr + kk,           &Bs[buf][(w * 32) * 32]);
        gload16(bPtr + kk + rowskip, &Bs[buf][(w * 32 + 16) * 32]);
    };

    stage(0, 0); stage(1, 32); stage(2, 64);
    asm volatile("s_waitcnt vmcnt(6)" ::: "memory");   // tile 0 landed; 1,2 in flight
    __builtin_amdgcn_s_barrier();
    asm volatile("" ::: "memory");

    for (int t = 0; t < NT; t++) {
        const int cur = t & 3;
        if (t + 3 < NT) stage((t + 3) & 3, (t + 3) * 32);

        bfrag af[2], bf[4];
#pragma unroll
        for (int i = 0; i < 2; i++)
            af[i] = *(const bfrag*)(&As[cur][(wm * 32 + i * 16 + l16) * 32 + quad * 8]);
#pragma unroll
        for (int j = 0; j < 4; j++)
            bf[j] = *(const bfrag*)(&Bs[cur][(wn * 64 + j * 16 + l16) * 32 + quad * 8]);
#pragma unroll
        for (int i = 0; i < 2; i++)
#pragma unroll
            for (int j = 0; j < 4; j++)
                acc[i][j] = __builtin_amdgcn_mfma_f32_16x16x32_bf16(af[i], bf[j], acc[i][j], 0, 0, 0);

        if (t + 3 < NT)      asm volatile("s_waitcnt vmcnt(6)" ::: "memory");  // t+1 landed
        else if (t + 2 < NT) asm volatile("s_waitcnt vmcnt(3)" ::: "memory");
        else if (t + 1 < NT) asm volatile("s_waitcnt vmcnt(0)" ::: "memory");
        if (t + 1 < NT) {
            __builtin_amdgcn_s_barrier();
            asm volatile("" ::: "memory");
        }
    }

#pragma unroll
    for (int i = 0; i < 2; i++) {
#pragma unroll
        for (int j = 0; j < 4; j++) {
            const int col = tn * 128 + wn * 64 + j * 16 + l16;
#pragma unroll
            for (int r = 0; r < 4; r++) {
                const int row = tm * 64 + wm * 32 + i * 16 + quad * 4 + r;
                C[(size_t)row * N + col] = acc[i][j][r];
            }
        }
    }
}

// ---------------- flash attention (causal), S^T formulation, 128-key tiles ----------------
// [round-10 version, measured 54.8us flash / 250.3us total -- best of 13 variants.
//  r11 (split+backfill, 67.5) and r12 (LPT+split, 58.8) showed the split's per-block
//  fixed costs eat the concurrency gain; this direct mapping is the structure's floor.]
// Block map: g = gy<64 ? gy : 191-gy, so blocks i and i+256 (co-resident under the
// (i,i+256) round-robin pairing) get complementary g and 127-g -> 17 visits per CU.
// 512 blocks x 256 threads = 4 waves, 64KB LDS -> 2 blocks/CU. Block = (kv head, 16-row
// q-group g); wave w = q-head kv*4+w on the same 16 rows (GQA-shared staging). S^T via
// swapped-operand 16x16x32 MFMA: lane holds P[q=l16][key=quad*4+r] = the 16x16x16 MFMA
// operand layout, so PV runs as mfma_f32_16x16x16bf16_1k with no P LDS round-trip.
// O accumulated as O[q=l16][d=ct*16+quad*4+r]. Streaming softmax (no running max).
__global__ __launch_bounds__(256) void flash_attn(const u16* __restrict__ Qr, const u16* __restrict__ Kr,
                                                  const u16* __restrict__ Vt, u16* __restrict__ attnout) {
    const int bid = blockIdx.x;
    const int kv = bid & 3;
    const int gy = bid >> 2;          // 0..127
    const int g = (gy < 64) ? gy : (191 - gy);   // complementary pairing across bid+-256
    const int tid = threadIdx.x;
    const int w = tid >> 6, lane = tid & 63, quad = lane >> 4, l16 = lane & 15;
    const int h = kv * 4 + w;         // wave's q-head

    __shared__ u16 ks[128 * 128];     // K tile [128 keys][128 d], swizzled 16B chunks
    __shared__ u16 vt[128 * 128];     // V^T tile [128 d][128 keys], swizzled 16B chunks

    // Q fragments (B-operand layout: rows q=l16, k at quad*8)
    bfrag aq[4];
    const u16* qbase = Qr + ((size_t)(h * 2048 + g * 16 + l16)) * 128 + quad * 8;
#pragma unroll
    for (int kb = 0; kb < 4; kb++) aq[kb] = *(const bfrag*)(qbase + kb * 32);

    f4 oacc[8];
#pragma unroll
    for (int ct = 0; ct < 8; ct++) oacc[ct] = f4{0.f, 0.f, 0.f, 0.f};
    float psum = 0.f;                 // per-lane partial row-sum for q = l16

    const int qg = g * 16 + l16;      // this lane's global q row
    const int ktn = g / 8 + 1;        // 128-key tiles for rows [g*16, g*16+16)
    const float C = 0.08838834764831845f * 1.4426950408889634f;  // (1/sqrt(128))*log2(e)
    const u16* kbase = Kr + (size_t)kv * 2048 * 128;
    const u16* vbase = Vt + (size_t)kv * 128 * 2048;

    for (int kt = 0; kt < ktn; kt++) {
        __syncthreads();
        // stage K [128][128]: 2048 chunks of 16B, 8 per thread
#pragma unroll
        for (int i = 0; i < 8; i++) {
            const int ci = (w * 8 + i) * 64 + lane;
            const int r = ci >> 4, c = (ci & 15) ^ (r & 15);
            gload16(kbase + (size_t)(kt * 128 + r) * 128 + c * 8, &ks[(w * 8 + i) * 512]);
        }
        // stage V^T [128 d][128 keys]: 2048 chunks
#pragma unroll
        for (int i = 0; i < 8; i++) {
            const int ci = (w * 8 + i) * 64 + lane;
            const int r = ci >> 4, c = (ci & 15) ^ (r & 15);
            gload16(vbase + (size_t)r * 2048 + kt * 128 + c * 8, &vt[(w * 8 + i) * 512]);
        }
        __syncthreads();

        // S^T: D[key][q] over 128 keys; A = K-frag (rows key), B = aq
        f4 sc[8];
#pragma unroll
        for (int nt = 0; nt < 8; nt++) {
            f4 c = f4{0.f, 0.f, 0.f, 0.f};
#pragma unroll
            for (int kb = 0; kb < 4; kb++) {
                bfrag a = *(const bfrag*)(&ks[((nt * 16 + l16) * 16 + ((quad + kb * 4) ^ l16)) * 8]);
                c = __builtin_amdgcn_mfma_f32_16x16x32_bf16(a, aq[kb], c, 0, 0, 0);
            }
            sc[nt] = c;
        }

        if (kt == ktn - 1) {          // only the diagonal tile needs causal masking
#pragma unroll
            for (int nt = 0; nt < 8; nt++) {
                const int key = kt * 128 + nt * 16 + quad * 4;
#pragma unroll
                for (int r = 0; r < 4; r++)
                    if (key + r > qg) sc[nt][r] = -INFINITY;
            }
        }

        // streaming softmax + in-lane P pack (A/B-operand layout for 16x16x16)
        s4 pa[8];
#pragma unroll
        for (int nt = 0; nt < 8; nt++) {
#pragma unroll
            for (int r = 0; r < 4; r++) {
                const float p = exp2f(fminf(sc[nt][r] * C, 40.f));
                psum += p;
                pa[nt][r] = (short)f2bf(p);
            }
        }

        // O[q][d] += P*V via 16x16x16: A = V^T frag (rows d), B = P
#pragma unroll
        for (int nt = 0; nt < 8; nt++) {
#pragma unroll
            for (int ct = 0; ct < 8; ct++) {
                const int d = ct * 16 + l16;
                s4 a = *(const s4*)(&vt[(d * 16 + ((nt * 2 + (quad >> 1)) ^ l16)) * 8 + (quad & 1) * 4]);
                oacc[ct] = __builtin_amdgcn_mfma_f32_16x16x16bf16_1k(a, pa[nt], oacc[ct], 0, 0, 0);
            }
        }
    }

    // epilogue: reduce psum over the 4 quads sharing q=l16, normalize, vector-store
    float s = psum;
    s += __shfl_xor(s, 16, 64);
    s += __shfl_xor(s, 32, 64);
    const float inv_l = 1.0f / s;
    u16* orow = attnout + (size_t)qg * 2048 + h * 128;
#pragma unroll
    for (int ct = 0; ct < 8; ct++) {
        u16x4 o;
#pragma unroll
        for (int r = 0; r < 4; r++) o[r] = f2bf(oacc[ct][r] * inv_l);
        *(u16x4*)(orow + ct * 16 + quad * 4) = o;
    }
}

// ---------------- launch ----------------
extern "C" void kernel_launch(void* const* d_in, const int* in_sizes, int n_in,
                              void* d_out, int out_size, void* d_ws, size_t ws_size,
                              hipStream_t stream) {
    const float* X  = (const float*)d_in[0];
    const float* wq = (const float*)d_in[3];
    const float* bq = (const float*)d_in[4];
    const float* wk = (const float*)d_in[5];
    const float* bk = (const float*)d_in[6];
    const float* wv = (const float*)d_in[7];
    const float* bv = (const float*)d_in[8];
    const float* wo = (const float*)d_in[9];

    char* ws = (char*)d_ws;
    u16*   Xb      = (u16*)(ws);                         // 8 MB
    u16*   Wqkv    = (u16*)(ws + 8388608);               // 12 MB  [3072][2048]
    u16*   Wo      = (u16*)(ws + 20971520);              // 8 MB
    float* biasqkv = (float*)(ws + 29360128);            // 12 KB
    u16*   Qr      = (u16*)(ws + 54538240);              // 8 MB   [16][2048][128]
    u16*   Kr      = (u16*)(ws + 62926848);              // 2 MB   [4][2048][128]
    u16*   attnout = (u16*)(ws + 67121152);              // 8 MB   [2048][2048]
    u16*   Vt      = (u16*)(ws + 75509760);              // 2 MB   [4][128][2048]

    prep<<<2048, 256, 0, stream>>>(X, wq, wk, wv, wo, bq, bk, bv, Xb, Wqkv, Wo, biasqkv);
    gemm_qkv_rope<<<dim3(24, 32), 256, 0, stream>>>(Xb, Wqkv, biasqkv, Qr, Kr, Vt);
    flash_attn<<<512, 256, 0, stream>>>(Qr, Kr, Vt, attnout);
    gemm_bt<<<dim3(16, 32), 256, 0, stream>>>(attnout, Wo, (float*)d_out, 2048, 2048, 2048);
}